// Round 9
// baseline (135.298 us; speedup 1.0000x reference)
//
#include <hip/hip_runtime.h>
#include <hip/hip_bf16.h>
#include <math.h>

#define BB 1024
#define DD 64
#define HH 128

typedef _Float16 half8 __attribute__((ext_vector_type(8)));
typedef __fp16 fp16x2 __attribute__((ext_vector_type(2)));
typedef float floatx4 __attribute__((ext_vector_type(4)));

union H8 { fp16x2 p[4]; half8 v; };

// async global -> LDS, 16B per lane. lds base must be wave-uniform; HW adds lane*16.
__device__ __forceinline__ void async_cp16(const float* g, float* lds_wave_base) {
    __builtin_amdgcn_global_load_lds(
        (const __attribute__((address_space(1))) unsigned int*)g,
        (__attribute__((address_space(3))) unsigned int*)lds_wave_base,
        16, 0, 0);
}

// ---------------------------------------------------------------------------
// Prep: c1[i,h] = x_i @ (Wi+Wd) + b1  (f32)
//       c2P = x_j @ (Wj-Wd) in hh-split MFMA C-fragment order:
//         c2P[(j>>4)*2048 + (h>>6)*1024 + ((h>>4)&3)*256
//             + ((j&15)>>2)*64 + (h&15)*4 + (j&3)]
//       wpack (f16) = Wab in per-lane MFMA B-fragment order, hh-major.
// Grid 128 x 256. Block = 8 i rows x 32 h-quads; W1 reads are float4.
// ---------------------------------------------------------------------------
__global__ __launch_bounds__(256) void prep_kernel(
    const float* __restrict__ x, const float* __restrict__ W1,
    const float* __restrict__ b1,
    float* __restrict__ c1, float* __restrict__ c2P,
    _Float16* __restrict__ wpack)
{
    __shared__ float xs[8][DD];
    const int t = threadIdx.x;
    const int i0 = blockIdx.x * 8;
    xs[t >> 6][t & 63] = x[i0 * DD + t];
    xs[4 + (t >> 6)][t & 63] = x[i0 * DD + 256 + t];
    __syncthreads();

    const int ii = t >> 5;           // 0..7
    const int h4 = t & 31;           // h-quad
    const int h = h4 * 4;
    const int i = i0 + ii;

    float4 a1 = {0.f, 0.f, 0.f, 0.f};
    float4 a2 = {0.f, 0.f, 0.f, 0.f};
    #pragma unroll 4
    for (int k = 0; k < DD; k++) {
        float4 wi = *(const float4*)(W1 + k * HH + h);
        float4 wj = *(const float4*)(W1 + (DD + k) * HH + h);
        float4 wd = *(const float4*)(W1 + (2 * DD + k) * HH + h);
        float xv = xs[ii][k];
        a1.x = fmaf(xv, wi.x + wd.x, a1.x);
        a1.y = fmaf(xv, wi.y + wd.y, a1.y);
        a1.z = fmaf(xv, wi.z + wd.z, a1.z);
        a1.w = fmaf(xv, wi.w + wd.w, a1.w);
        a2.x = fmaf(xv, wj.x - wd.x, a2.x);
        a2.y = fmaf(xv, wj.y - wd.y, a2.y);
        a2.z = fmaf(xv, wj.z - wd.z, a2.z);
        a2.w = fmaf(xv, wj.w - wd.w, a2.w);
    }
    float4 b1v = *(const float4*)(b1 + h);
    float4 c1v = {a1.x + b1v.x, a1.y + b1v.y, a1.z + b1v.z, a1.w + b1v.w};
    *(float4*)(c1 + i * HH + h) = c1v;

    // scatter a2 into hh-split fragment order
    const int jl = i & 15;
    float* cb = c2P + (i >> 4) * 2048 + (h >> 6) * 1024 + ((h >> 4) & 3) * 256 + (jl & 3);
    const int p0 = (jl >> 2) * 16 + (h & 15);
    cb[(p0 + 0) * 4] = a2.x;
    cb[(p0 + 1) * 4] = a2.y;
    cb[(p0 + 2) * 4] = a2.z;
    cb[(p0 + 3) * 4] = a2.w;

    if (blockIdx.x < 32) {
        int f = blockIdx.x * 256 + t;        // 0..8191
        int jj = f & 7;
        int l  = (f >> 3) & 63;
        int u  = f >> 9;                     // hh*8 + t4*2 + s
        int s  = u & 1, t4 = (u >> 1) & 3, hh = u >> 3;
        int k  = s * 32 + ((l >> 4) << 3) + jj;
        int hcol = hh * 64 + t4 * 16 + (l & 15);
        wpack[f] = (_Float16)W1[(3 * DD + k) * HH + hcol];
    }
}

// ---------------------------------------------------------------------------
// Pair kernel: Sp[jq][i][hh*64+..] = sum_{j in quarter jq}
//                relu(|x_i-x_j| @ Wab[:,h-half] + c1[i] + c2[j])
// Grid 2048 = 256 ig x 2 hh x 4 jq. Block = 4 waves = 4 i, one h-half.
// j-quarter = 8 supertiles of 32 j (2 subtiles of 16) -> 8 barriers.
// xs (f32, XOR-swizzled) + c2 half-tiles staged async, double-buffered;
// staging pointers strength-reduced (+= stride per supertile).
// A-operand built in f16 via v_cvt_pkrtz (2 conv/instr, abs folded).
// ---------------------------------------------------------------------------
__global__ __launch_bounds__(256, 4) void pair_kernel(
    const float* __restrict__ x, const float* __restrict__ c1,
    const float* __restrict__ c2P, const _Float16* __restrict__ wpack,
    float* __restrict__ Sp)
{
    __shared__ __align__(16) float xs[2][2048];   // 2 x 8 KB (32 j x 64 k, swizzled)
    __shared__ __align__(16) float c2s[2][2048];  // 2 x 8 KB (2 x 16j fragment groups)

    const int t = threadIdx.x;
    const int wave = t >> 6;
    const int l = t & 63;
    const int quad = l >> 4, lm = l & 15;
    const int bid = blockIdx.x;
    const int ig = bid >> 3;
    const int hh = (bid >> 2) & 1;
    const int jq = bid & 3;
    const int i = ig * 4 + wave;
    const int j0base = jq * 256;
    const int sw = lm & 7;

    // per-thread staging sources (strength-reduced: bump by stride per supertile)
    const int r0 = t >> 4;                       // row 0..15 within 16-row group
    const int cp = (t & 15) ^ (r0 & 7);          // swizzled source chunk
    const float* xsrc = x + (j0base + r0) * DD + cp * 4;       // rows r0 / r0+16
    const float* csrc = c2P + (j0base >> 4) * 2048 + hh * 1024 + t * 4;

    // stage supertile 0 (async)
    async_cp16(xsrc,           &xs[0][0]   + wave * 256);
    async_cp16(xsrc + 16 * DD, &xs[0][1024] + wave * 256);
    async_cp16(csrc,           &c2s[0][0]   + wave * 256);
    async_cp16(csrc + 2048,    &c2s[0][1024] + wave * 256);
    const float* xpre = xsrc + 32 * DD;
    const float* cpre = csrc + 4096;

    // wave-private register data (overlaps staging)
    float xi[16];
    {
        const float* xg = x + i * DD + quad * 8;
        *(float4*)(xi)      = *(const float4*)(xg);
        *(float4*)(xi + 4)  = *(const float4*)(xg + 4);
        *(float4*)(xi + 8)  = *(const float4*)(xg + 32);
        *(float4*)(xi + 12) = *(const float4*)(xg + 36);
    }
    float c1r[4];
    #pragma unroll
    for (int t4 = 0; t4 < 4; t4++)
        c1r[t4] = c1[i * HH + hh * 64 + t4 * 16 + lm];
    half8 wf[8];
    #pragma unroll
    for (int u = 0; u < 8; u++)
        wf[u] = *(const half8*)(wpack + ((hh * 8 + u) * 64 + l) * 8);

    float S[4] = {0.f, 0.f, 0.f, 0.f};

    #pragma unroll 1
    for (int tile = 0; tile < 8; ++tile) {
        const int cur = tile & 1;
        __syncthreads();   // staged data for 'tile' landed; other buffer free

        if (tile < 7) {    // prefetch next supertile (async), pointer-bumped
            const int nb = cur ^ 1;
            async_cp16(xpre,           &xs[nb][0]    + wave * 256);
            async_cp16(xpre + 16 * DD, &xs[nb][1024] + wave * 256);
            async_cp16(cpre,           &c2s[nb][0]    + wave * 256);
            async_cp16(cpre + 2048,    &c2s[nb][1024] + wave * 256);
            xpre += 32 * DD;
            cpre += 4096;
        }

        #pragma unroll
        for (int st = 0; st < 2; st++) {
            // acc init = c2 (fragment-ordered LDS b128) + c1
            floatx4 acc[4];
            #pragma unroll
            for (int t4 = 0; t4 < 4; t4++) {
                float4 c2v = *(const float4*)(&c2s[cur][st * 1024 + t4 * 256 + l * 4]);
                acc[t4][0] = c2v.x + c1r[t4];
                acc[t4][1] = c2v.y + c1r[t4];
                acc[t4][2] = c2v.z + c1r[t4];
                acc[t4][3] = c2v.w + c1r[t4];
            }

            // A fragment: row r = st*16+lm, chunks quad*2,+1,+8,+9, swizzle sw
            const float* xb = &xs[cur][(st * 16 + lm) * 64];
            float4 a0 = *(const float4*)(xb + (((quad * 2)     ^ sw) << 2));
            float4 a1 = *(const float4*)(xb + (((quad * 2 + 1) ^ sw) << 2));
            float4 a2 = *(const float4*)(xb + (((quad * 2 + 8) ^ sw) << 2));
            float4 a3 = *(const float4*)(xb + (((quad * 2 + 9) ^ sw) << 2));
            H8 af0, af1;
            af0.p[0] = __builtin_amdgcn_cvt_pkrtz(fabsf(xi[0] - a0.x),  fabsf(xi[1] - a0.y));
            af0.p[1] = __builtin_amdgcn_cvt_pkrtz(fabsf(xi[2] - a0.z),  fabsf(xi[3] - a0.w));
            af0.p[2] = __builtin_amdgcn_cvt_pkrtz(fabsf(xi[4] - a1.x),  fabsf(xi[5] - a1.y));
            af0.p[3] = __builtin_amdgcn_cvt_pkrtz(fabsf(xi[6] - a1.z),  fabsf(xi[7] - a1.w));
            af1.p[0] = __builtin_amdgcn_cvt_pkrtz(fabsf(xi[8] - a2.x),  fabsf(xi[9] - a2.y));
            af1.p[1] = __builtin_amdgcn_cvt_pkrtz(fabsf(xi[10] - a2.z), fabsf(xi[11] - a2.w));
            af1.p[2] = __builtin_amdgcn_cvt_pkrtz(fabsf(xi[12] - a3.x), fabsf(xi[13] - a3.y));
            af1.p[3] = __builtin_amdgcn_cvt_pkrtz(fabsf(xi[14] - a3.z), fabsf(xi[15] - a3.w));

            #pragma unroll
            for (int t4 = 0; t4 < 4; t4++) {
                acc[t4] = __builtin_amdgcn_mfma_f32_16x16x32_f16(af0.v, wf[t4 * 2 + 0], acc[t4], 0, 0, 0);
                acc[t4] = __builtin_amdgcn_mfma_f32_16x16x32_f16(af1.v, wf[t4 * 2 + 1], acc[t4], 0, 0, 0);
            }
            #pragma unroll
            for (int t4 = 0; t4 < 4; t4++) {
                S[t4] += fmaxf(acc[t4][0], 0.f);
                S[t4] += fmaxf(acc[t4][1], 0.f);
                S[t4] += fmaxf(acc[t4][2], 0.f);
                S[t4] += fmaxf(acc[t4][3], 0.f);
            }
        }
    }

    // reduce across the 4 quads (same h = lm+16*t4, different j-rows)
    #pragma unroll
    for (int t4 = 0; t4 < 4; t4++) {
        S[t4] += __shfl_xor(S[t4], 16, 64);
        S[t4] += __shfl_xor(S[t4], 32, 64);
    }
    if (quad == 0) {
        #pragma unroll
        for (int t4 = 0; t4 < 4; t4++)
            Sp[(jq * BB + i) * HH + hh * 64 + t4 * 16 + lm] = S[t4];
    }
}

// ---------------------------------------------------------------------------
// Finish: per row i:  m = (b2 + (mean_j S) @ W2)/tau ; h = relu(m@Wa+ba);
//   y = h + x@Wr + br; out = LayerNorm(y)*gamma+beta.
// Grid 128 x 256. Block = 8 i rows x 32 h-quads; weights read as float4.
// ---------------------------------------------------------------------------
__global__ __launch_bounds__(256) void finish_kernel(
    const float* __restrict__ Sp, const float* __restrict__ W2,
    const float* __restrict__ b2, const float* __restrict__ x,
    const float* __restrict__ Wt, const float* __restrict__ bt,
    const float* __restrict__ Wa, const float* __restrict__ ba,
    const float* __restrict__ Wr, const float* __restrict__ br,
    const float* __restrict__ gamma, const float* __restrict__ beta,
    float* __restrict__ out)
{
    __shared__ float Srow[8][HH];
    __shared__ float mrow[8][HH];
    __shared__ float xrowS[8][DD];
    __shared__ float taus[8];
    const int t = threadIdx.x;
    const int ii = t >> 5;          // 0..7
    const int h4 = t & 31;
    const int h = h4 * 4;
    const int i0 = blockIdx.x * 8;
    const int i = i0 + ii;

    {
        float4 s = {0.f, 0.f, 0.f, 0.f};
        #pragma unroll
        for (int q = 0; q < 4; q++) {
            float4 v = *(const float4*)(Sp + (q * BB + i) * HH + h);
            s.x += v.x; s.y += v.y; s.z += v.z; s.w += v.w;
        }
        const float inv = 1.0f / (float)BB;
        float4 sm = {s.x * inv, s.y * inv, s.z * inv, s.w * inv};
        *(float4*)(&Srow[ii][h]) = sm;
    }
    xrowS[t >> 6][t & 63] = x[i0 * DD + t];
    xrowS[4 + (t >> 6)][t & 63] = x[i0 * DD + 256 + t];

    {
        float p = x[i * DD + h4] * Wt[h4] + x[i * DD + 32 + h4] * Wt[32 + h4];
        #pragma unroll
        for (int off = 16; off; off >>= 1) p += __shfl_xor(p, off, 64);
        if (h4 == 0) {
            float z = p + bt[0];
            float sp = (z > 20.f) ? z : log1pf(expf(z));
            taus[ii] = fmaxf(sp, 0.01f) + 1.0f;
        }
    }
    __syncthreads();

    float4 acc = *(const float4*)(b2 + h);
    #pragma unroll 8
    for (int k = 0; k < HH; k++) {
        float4 w = *(const float4*)(W2 + k * HH + h);
        float sv = Srow[ii][k];
        acc.x = fmaf(sv, w.x, acc.x); acc.y = fmaf(sv, w.y, acc.y);
        acc.z = fmaf(sv, w.z, acc.z); acc.w = fmaf(sv, w.w, acc.w);
    }
    const float itau = 1.0f / taus[ii];
    float4 mv = {acc.x * itau, acc.y * itau, acc.z * itau, acc.w * itau};
    *(float4*)(&mrow[ii][h]) = mv;
    __syncthreads();

    float4 a2 = *(const float4*)(ba + h);
    #pragma unroll 8
    for (int k = 0; k < HH; k++) {
        float4 w = *(const float4*)(Wa + k * HH + h);
        float sv = mrow[ii][k];
        a2.x = fmaf(sv, w.x, a2.x); a2.y = fmaf(sv, w.y, a2.y);
        a2.z = fmaf(sv, w.z, a2.z); a2.w = fmaf(sv, w.w, a2.w);
    }
    float4 brv = *(const float4*)(br + h);
    float4 y = {fmaxf(a2.x, 0.f) + brv.x, fmaxf(a2.y, 0.f) + brv.y,
                fmaxf(a2.z, 0.f) + brv.z, fmaxf(a2.w, 0.f) + brv.w};
    #pragma unroll 8
    for (int d = 0; d < DD; d++) {
        float4 w = *(const float4*)(Wr + d * HH + h);
        float xv = xrowS[ii][d];
        y.x = fmaf(xv, w.x, y.x); y.y = fmaf(xv, w.y, y.y);
        y.z = fmaf(xv, w.z, y.z); y.w = fmaf(xv, w.w, y.w);
    }

    float p = y.x + y.y + y.z + y.w;
    #pragma unroll
    for (int off = 16; off; off >>= 1) p += __shfl_xor(p, off, 64);
    float mu = p * (1.0f / (float)HH);
    float4 dy = {y.x - mu, y.y - mu, y.z - mu, y.w - mu};
    float q = dy.x * dy.x + dy.y * dy.y + dy.z * dy.z + dy.w * dy.w;
    #pragma unroll
    for (int off = 16; off; off >>= 1) q += __shfl_xor(q, off, 64);
    float rs = rsqrtf(q * (1.0f / (float)HH) + 1e-5f);
    float4 gv = *(const float4*)(gamma + h);
    float4 bv = *(const float4*)(beta + h);
    float4 o = {dy.x * rs * gv.x + bv.x, dy.y * rs * gv.y + bv.y,
                dy.z * rs * gv.z + bv.z, dy.w * rs * gv.w + bv.w};
    *(float4*)(out + i * HH + h) = o;
}

// ---------------------------------------------------------------------------
extern "C" void kernel_launch(void* const* d_in, const int* in_sizes, int n_in,
                              void* d_out, int out_size, void* d_ws, size_t ws_size,
                              hipStream_t stream)
{
    const float* x     = (const float*)d_in[0];
    const float* W1    = (const float*)d_in[1];
    const float* b1    = (const float*)d_in[2];
    const float* W2    = (const float*)d_in[3];
    const float* b2    = (const float*)d_in[4];
    const float* Wt    = (const float*)d_in[5];
    const float* bt    = (const float*)d_in[6];
    const float* Wa    = (const float*)d_in[7];
    const float* ba    = (const float*)d_in[8];
    const float* Wr    = (const float*)d_in[9];
    const float* br    = (const float*)d_in[10];
    const float* gamma = (const float*)d_in[11];
    const float* beta  = (const float*)d_in[12];
    float* out = (float*)d_out;

    char* ws = (char*)d_ws;
    float*     c1    = (float*)(ws);                         // 512 KB
    float*     c2P   = (float*)(ws + (512 << 10));           // 512 KB
    _Float16*  wpack = (_Float16*)(ws + (1024 << 10));       // 16 KB
    float*     Sp    = (float*)(ws + (1056 << 10));          // 2 MB

    prep_kernel<<<128, 256, 0, stream>>>(x, W1, b1, c1, c2P, wpack);
    pair_kernel<<<2048, 256, 0, stream>>>(x, c1, c2P, wpack, Sp);
    finish_kernel<<<128, 256, 0, stream>>>(Sp, W2, b2, x, Wt, bt,
                                           Wa, ba, Wr, br, gamma, beta, out);
}